// Round 1
// baseline (168.856 us; speedup 1.0000x reference)
//
#include <hip/hip_runtime.h>
#include <math.h>

#define VOCAB 100000
#define EMB   128
#define BATCH 16384
#define CTX   20
#define NEG   20
#define NSCORE (NEG + 1)   // target + negatives

__device__ __forceinline__ float dot4(float4 a, float4 b) {
    return fmaf(a.x, b.x, fmaf(a.y, b.y, fmaf(a.z, b.z, a.w * b.w)));
}

// softplus(x) = log(1+exp(x)); x clamped to [-10,10] upstream.
__device__ __forceinline__ float fast_softplus(float x) {
    return __logf(1.0f + __expf(x));
}

// 32 lanes per batch row (one float4 column each) -> 8 rows per 256-thread
// block, grid = 2048 = 8 blocks/CU = 32 waves/CU (full residency).
// Previous 16-lane/row version capped at 16 waves/CU and was latency-bound
// (VALUBusy 11%, HBM 37%, Occupancy 30%).
__global__ __launch_bounds__(256, 8) void cbow_loss_kernel(
    const int*   __restrict__ pos_target,     // [B]
    const int*   __restrict__ pos_contexts,   // [B, C]
    const int*   __restrict__ pos_negatives,  // [B, N]
    const float* __restrict__ context_table,  // [VOCAB, 128]
    const float* __restrict__ output_table,   // [VOCAB, 128]
    float*       __restrict__ out)            // [1]
{
    const int tid  = threadIdx.x;
    const int lane = tid & 63;
    const int wave = tid >> 6;          // 0..3
    const int half = lane >> 5;         // 0..1
    const int sub  = lane & 31;         // lane within half-wave

    const int row = blockIdx.x * 8 + wave * 2 + half;

    const float4* ctab = (const float4*)context_table;  // row stride = 32 float4
    const float4* otab = (const float4*)output_table;

    // ---- cooperative index fetch (coalesced within each half-wave) ----
    int cidx = (sub < CTX) ? pos_contexts[row * CTX + sub] : 0;
    int sidx = (sub == 0) ? pos_target[row]
             : (sub <= NEG ? pos_negatives[row * NEG + sub - 1] : 0);

    // per-half-wave broadcast of index j (j is compile-time)
    auto ctx_idx = [&](int j) { return __shfl(cidx, j, 32); };
    auto sc_idx  = [&](int j) { return __shfl(sidx, j, 32); };

    // ================= phase 1: context sum (20 rows, chunks of 5) =========
    // lane owns the float4 at column `sub` of the 32-float4 row.
    float4 acc = make_float4(0.f, 0.f, 0.f, 0.f);
    {
        float4 buf[2][5];
#pragma unroll
        for (int j = 0; j < 5; ++j)              // prologue: chunk 0
            buf[0][j] = ctab[ctx_idx(j) * 32 + sub];
#pragma unroll
        for (int g = 0; g < 4; ++g) {
            if (g + 1 < 4) {                     // prefetch chunk g+1
#pragma unroll
                for (int j = 0; j < 5; ++j)
                    buf[(g + 1) & 1][j] = ctab[ctx_idx((g + 1) * 5 + j) * 32 + sub];
            }
#pragma unroll
            for (int j = 0; j < 5; ++j) {        // accumulate chunk g
                const float4 a = buf[g & 1][j];
                acc.x += a.x; acc.y += a.y; acc.z += a.z; acc.w += a.w;
            }
        }
    }

    // ================= phase 2: 21 score dots (chunks of 7) ================
    float part[NSCORE];
    {
        float4 sbuf[2][7];
#pragma unroll
        for (int j = 0; j < 7; ++j)              // prologue: chunk 0
            sbuf[0][j] = otab[sc_idx(j) * 32 + sub];
#pragma unroll
        for (int g = 0; g < 3; ++g) {
            if (g + 1 < 3) {                     // prefetch chunk g+1
#pragma unroll
                for (int j = 0; j < 7; ++j)
                    sbuf[(g + 1) & 1][j] = otab[sc_idx((g + 1) * 7 + j) * 32 + sub];
            }
#pragma unroll
            for (int j = 0; j < 7; ++j)
                part[g * 7 + j] = dot4(acc, sbuf[g & 1][j]);
        }
    }

    // ---- 21 butterfly reductions over 32 lanes (5 steps) ----
    // xor masks <=16 never cross the 32-lane half boundary, so default
    // width-64 shfl_xor is correct here.
#pragma unroll
    for (int s = 16; s >= 1; s >>= 1) {
#pragma unroll
        for (int n = 0; n < NSCORE; ++n) part[n] += __shfl_xor(part[n], s);
    }

    // ---- loss: softplus(-pos) + sum softplus(neg); one lane per row ----
    __shared__ float sdata[8];
    if (sub == 0) {
        float ps = fminf(fmaxf(part[0], -10.f), 10.f);
        float loss = fast_softplus(-ps);
#pragma unroll
        for (int n = 1; n < NSCORE; ++n) {
            float ns = fminf(fmaxf(part[n], -10.f), 10.f);
            loss += fast_softplus(ns);
        }
        sdata[wave * 2 + half] = loss;
    }
    __syncthreads();

    // ---- block reduction: 8 half-wave results -> 1 atomic ----
    if (tid == 0) {
        float s = 0.f;
#pragma unroll
        for (int i = 0; i < 8; ++i) s += sdata[i];
        atomicAdd(out, s * (1.0f / (float)BATCH));
    }
}

extern "C" void kernel_launch(void* const* d_in, const int* in_sizes, int n_in,
                              void* d_out, int out_size, void* d_ws, size_t ws_size,
                              hipStream_t stream) {
    const int*   pos_target    = (const int*)d_in[0];
    const int*   pos_contexts  = (const int*)d_in[1];
    const int*   pos_negatives = (const int*)d_in[2];
    const float* context_table = (const float*)d_in[3];
    const float* output_table  = (const float*)d_in[4];
    float* out = (float*)d_out;

    // d_out is poisoned 0xAA before every timed launch; memset node is
    // graph-capturable.
    hipMemsetAsync(out, 0, sizeof(float), stream);

    const int rows_per_block = 8;   // 4 waves x 2 half-waves
    const int grid = BATCH / rows_per_block;  // 2048
    cbow_loss_kernel<<<grid, 256, 0, stream>>>(
        pos_target, pos_contexts, pos_negatives, context_table, output_table, out);
}

// Round 2
// 155.075 us; speedup vs baseline: 1.0889x; 1.0889x over previous
//
#include <hip/hip_runtime.h>
#include <math.h>

#define VOCAB 100000
#define EMB   128
#define BATCH 16384
#define CTX   20
#define NEG   20
#define NSCORE (NEG + 1)   // target + negatives

__device__ __forceinline__ float dot4(float4 a, float4 b) {
    return fmaf(a.x, b.x, fmaf(a.y, b.y, fmaf(a.z, b.z, a.w * b.w)));
}

// softplus(x) = log(1+exp(x)); x clamped to [-10,10] upstream.
__device__ __forceinline__ float fast_softplus(float x) {
    return __logf(1.0f + __expf(x));
}

// 32 lanes per batch row (one float4 column each) -> 8 rows per 256-thread
// block, grid = 2048 = 8 blocks/CU = 32 waves/CU (full residency).
//
// Round-1 lesson: launch_bounds(256,8) caps VGPR at 64; keeping sbuf[2][7]
// + part[21] live spilled ~84 B/thread to scratch (WRITE_SIZE 32 KB -> 44 MB)
// and regressed 55 -> 71 us. This version consumes each chunk of 7 scores
// immediately (reduce + softplus accumulate) so the live set stays ~45-54
// VGPRs -- no spills at full occupancy.
__global__ __launch_bounds__(256, 8) void cbow_loss_kernel(
    const int*   __restrict__ pos_target,     // [B]
    const int*   __restrict__ pos_contexts,   // [B, C]
    const int*   __restrict__ pos_negatives,  // [B, N]
    const float* __restrict__ context_table,  // [VOCAB, 128]
    const float* __restrict__ output_table,   // [VOCAB, 128]
    float*       __restrict__ out)            // [1]
{
    const int tid  = threadIdx.x;
    const int lane = tid & 63;
    const int wave = tid >> 6;          // 0..3
    const int half = lane >> 5;         // 0..1
    const int sub  = lane & 31;         // lane within half-wave

    const int row = blockIdx.x * 8 + wave * 2 + half;

    const float4* ctab = (const float4*)context_table;  // row stride = 32 float4
    const float4* otab = (const float4*)output_table;

    // ---- cooperative index fetch (coalesced within each half-wave) ----
    int cidx = (sub < CTX) ? pos_contexts[row * CTX + sub] : 0;
    int sidx = (sub == 0) ? pos_target[row]
             : (sub <= NEG ? pos_negatives[row * NEG + sub - 1] : 0);

    // per-half-wave broadcast of index j (j is compile-time constant)
    auto ctx_idx = [&](int j) { return __shfl(cidx, j, 32); };
    auto sc_idx  = [&](int j) { return __shfl(sidx, j, 32); };

    // ================= phase 1: context sum (20 rows, dbuf chunks of 5) ====
    // lane owns the float4 at column `sub` of the 32-float4 row.
    float4 acc = make_float4(0.f, 0.f, 0.f, 0.f);
    {
        float4 buf[2][5];
#pragma unroll
        for (int j = 0; j < 5; ++j)              // prologue: chunk 0
            buf[0][j] = ctab[ctx_idx(j) * 32 + sub];
#pragma unroll
        for (int g = 0; g < 4; ++g) {
            if (g + 1 < 4) {                     // prefetch chunk g+1
#pragma unroll
                for (int j = 0; j < 5; ++j)
                    buf[(g + 1) & 1][j] = ctab[ctx_idx((g + 1) * 5 + j) * 32 + sub];
            }
#pragma unroll
            for (int j = 0; j < 5; ++j) {        // accumulate chunk g
                const float4 a = buf[g & 1][j];
                acc.x += a.x; acc.y += a.y; acc.z += a.z; acc.w += a.w;
            }
        }
    }

    // ================= phase 2: 21 score dots, 3 chunks of 7 ===============
    // Each chunk: 7 outstanding row loads -> 7 dots -> 7-wide butterfly
    // allreduce over 32 lanes -> clamp + softplus folded into `loss`.
    // part[] never exceeds 7 live values -> no spills under the 64-VGPR cap.
    float loss = 0.f;
#pragma unroll
    for (int g = 0; g < 3; ++g) {
        float4 sbuf[7];
#pragma unroll
        for (int j = 0; j < 7; ++j)
            sbuf[j] = otab[sc_idx(g * 7 + j) * 32 + sub];

        float part[7];
#pragma unroll
        for (int j = 0; j < 7; ++j)
            part[j] = dot4(acc, sbuf[j]);

        // butterfly allreduce over the 32 lanes of this half-wave; xor masks
        // <=16 never cross the half boundary, so default-width shfl is fine.
#pragma unroll
        for (int s = 16; s >= 1; s >>= 1) {
#pragma unroll
            for (int j = 0; j < 7; ++j) part[j] += __shfl_xor(part[j], s);
        }

#pragma unroll
        for (int j = 0; j < 7; ++j) {
            const float v = fminf(fmaxf(part[j], -10.f), 10.f);
            // score 0 is the positive target: softplus(-v); rest: softplus(v)
            loss += fast_softplus((g == 0 && j == 0) ? -v : v);
        }
    }

    // ---- block reduction: 8 half-wave results -> 1 atomic ----
    __shared__ float sdata[8];
    if (sub == 0) sdata[wave * 2 + half] = loss;
    __syncthreads();
    if (tid == 0) {
        float s = 0.f;
#pragma unroll
        for (int i = 0; i < 8; ++i) s += sdata[i];
        atomicAdd(out, s * (1.0f / (float)BATCH));
    }
}

extern "C" void kernel_launch(void* const* d_in, const int* in_sizes, int n_in,
                              void* d_out, int out_size, void* d_ws, size_t ws_size,
                              hipStream_t stream) {
    const int*   pos_target    = (const int*)d_in[0];
    const int*   pos_contexts  = (const int*)d_in[1];
    const int*   pos_negatives = (const int*)d_in[2];
    const float* context_table = (const float*)d_in[3];
    const float* output_table  = (const float*)d_in[4];
    float* out = (float*)d_out;

    // d_out is poisoned 0xAA before every timed launch; memset node is
    // graph-capturable.
    hipMemsetAsync(out, 0, sizeof(float), stream);

    const int rows_per_block = 8;   // 4 waves x 2 half-waves
    const int grid = BATCH / rows_per_block;  // 2048
    cbow_loss_kernel<<<grid, 256, 0, stream>>>(
        pos_target, pos_contexts, pos_negatives, context_table, output_table, out);
}